// Round 2
// baseline (1888.566 us; speedup 1.0000x reference)
//
#include <hip/hip_runtime.h>
#include <math.h>

#define BATCH 16
#define CH 512
#define HW 4096
#define NG 16
#define GS 32

typedef __attribute__((ext_vector_type(8))) short bf16x8;
typedef __attribute__((ext_vector_type(2))) short s16x2;
typedef __attribute__((ext_vector_type(4))) float f32x4;

__device__ __forceinline__ float b2f(short s) {
    union { unsigned u; float f; } c;
    c.u = ((unsigned)(unsigned short)s) << 16;
    return c.f;
}
__device__ __forceinline__ short f2b(float f) {
    union { float f; unsigned u; } c; c.f = f;
    unsigned u = c.u + 0x7FFFu + ((c.u >> 16) & 1u);
    return (short)(u >> 16);
}

// convert fp32 weights -> bf16 (8 elements/thread)
__global__ __launch_bounds__(256) void cvt_w(const float* __restrict__ a,
                                             short* __restrict__ o, int n8) {
    int idx = blockIdx.x * 256 + threadIdx.x;
    if (idx >= n8) return;
    long f = (long)idx * 8;
    f32x4 v0 = *(const f32x4*)(a + f);
    f32x4 v1 = *(const f32x4*)(a + f + 4);
    bf16x8 ob;
#pragma unroll
    for (int j = 0; j < 4; j++) { ob[j] = f2b(v0[j]); ob[4 + j] = f2b(v1[j]); }
    *(bf16x8*)(o + f) = ob;
}

// ---------------- GroupNorm1 stats over [32c x 4096n] contiguous fp32 -------
__global__ __launch_bounds__(256) void gn1_stats(const float* __restrict__ x,
                                                 float* __restrict__ stats) {
    int b = blockIdx.x >> 4, g = blockIdx.x & 15;
    const float* p = x + ((long)b * CH + g * GS) * HW;
    float s = 0.f, ss = 0.f;
    for (int i = threadIdx.x; i < (GS * HW) / 4; i += 256) {
        f32x4 v = *(const f32x4*)(p + i * 4);
#pragma unroll
        for (int j = 0; j < 4; j++) { float f = v[j]; s += f; ss += f * f; }
    }
    __shared__ float rs[256], rss[256];
    rs[threadIdx.x] = s; rss[threadIdx.x] = ss; __syncthreads();
    for (int off = 128; off; off >>= 1) {
        if (threadIdx.x < off) { rs[threadIdx.x] += rs[threadIdx.x + off]; rss[threadIdx.x] += rss[threadIdx.x + off]; }
        __syncthreads();
    }
    if (threadIdx.x == 0) {
        float mean = rs[0] / (GS * HW);
        float var = rss[0] / (GS * HW) - mean * mean;
        stats[(b * NG + g) * 2] = mean;
        stats[(b * NG + g) * 2 + 1] = rsqrtf(var + 1e-5f);
    }
}

// GN1 apply: write xn fp32 [c][n] (residual) and xnT bf16 [n][c] (GEMM operand)
__global__ __launch_bounds__(256) void gn1_apply(const float* __restrict__ x,
                                                 const float* __restrict__ stats,
                                                 const float* __restrict__ w,
                                                 const float* __restrict__ bias,
                                                 float* __restrict__ xn,
                                                 short* __restrict__ xnT) {
    __shared__ short tile[64 * 66];
    int b = blockIdx.z, c0 = blockIdx.y * 64, n0 = blockIdx.x * 64;
    int tid = threadIdx.x;
#pragma unroll
    for (int it = 0; it < 2; ++it) {
        int chunk = tid + it * 256;
        int cr = chunk >> 3, colc = (chunk & 7) * 8;
        int c = c0 + cr;
        long base = ((long)b * CH + c) * HW + n0 + colc;
        f32x4 v0 = *(const f32x4*)(x + base);
        f32x4 v1 = *(const f32x4*)(x + base + 4);
        int g = c >> 5;
        float mean = stats[(b * NG + g) * 2], rstd = stats[(b * NG + g) * 2 + 1];
        float sw = w[c] * rstd;
        float sb = bias[c] - mean * sw;
        f32x4 o0, o1;
#pragma unroll
        for (int j = 0; j < 4; j++) { o0[j] = v0[j] * sw + sb; o1[j] = v1[j] * sw + sb; }
        *(f32x4*)(xn + base) = o0;
        *(f32x4*)(xn + base + 4) = o1;
#pragma unroll
        for (int k = 0; k < 4; k++) {
            s16x2 t2;
            t2[0] = f2b(k < 2 ? o0[2 * k] : o1[2 * k - 4]);
            t2[1] = f2b(k < 2 ? o0[2 * k + 1] : o1[2 * k - 3]);
            *(s16x2*)(tile + cr * 66 + colc + 2 * k) = t2;
        }
    }
    __syncthreads();
#pragma unroll
    for (int it = 0; it < 2; ++it) {
        int chunk = tid + it * 256;
        int nr = chunk >> 3, colc = (chunk & 7) * 8;
        bf16x8 o;
#pragma unroll
        for (int j = 0; j < 8; j++) o[j] = tile[(colc + j) * 66 + nr];
        *(bf16x8*)(xnT + ((long)b * HW + n0 + nr) * CH + c0 + colc) = o;
    }
}

// ---------------- column (spatial) softmax stats for k (fp32 kvT) ----------
__global__ __launch_bounds__(512) void colstats_part(const float* __restrict__ kvT,
                                                     float* __restrict__ part) {
    int chunk = blockIdx.x, b = blockIdx.y;
    int d = threadIdx.x;
    float m = -1e30f, s = 0.f;
    for (int n = chunk * 512; n < (chunk + 1) * 512; ++n) {
        float x = kvT[((long)b * HW + n) * (2 * CH) + d];
        if (x > m) { s = s * expf(m - x) + 1.f; m = x; }
        else s += expf(x - m);
    }
    part[((b * 8 + chunk) * CH + d) * 2] = m;
    part[((b * 8 + chunk) * CH + d) * 2 + 1] = s;
}

__global__ __launch_bounds__(512) void colstats_reduce(const float* __restrict__ part,
                                                       float* __restrict__ cst) {
    int b = blockIdx.x, d = threadIdx.x;
    float m = -1e30f;
    for (int c = 0; c < 8; c++) m = fmaxf(m, part[((b * 8 + c) * CH + d) * 2]);
    float s = 0.f;
    for (int c = 0; c < 8; c++) {
        float mi = part[((b * 8 + c) * CH + d) * 2];
        float si = part[((b * 8 + c) * CH + d) * 2 + 1];
        s += si * expf(mi - m);
    }
    cst[(b * CH + d) * 2] = m;
    cst[(b * CH + d) * 2 + 1] = 1.f / s;
}

// transpose fp32 kvT [n][1024] slice -> bf16 out [c][n]; kmode: spatial softmax
__global__ __launch_bounds__(256) void transpose_apply(const float* __restrict__ kvT,
                                                       const float* __restrict__ cst,
                                                       short* __restrict__ out,
                                                       int off, int kmode) {
    __shared__ float tile[64 * 65];
    int b = blockIdx.z, c0 = blockIdx.y * 64, n0 = blockIdx.x * 64;
    int tid = threadIdx.x;
#pragma unroll
    for (int it = 0; it < 2; ++it) {
        int chunk = tid + it * 256;
        int nr = chunk >> 3, colc = (chunk & 7) * 8;
        long base = ((long)b * HW + n0 + nr) * (2 * CH) + off + c0 + colc;
        f32x4 v0 = *(const f32x4*)(kvT + base);
        f32x4 v1 = *(const f32x4*)(kvT + base + 4);
#pragma unroll
        for (int j = 0; j < 4; j++) {
            tile[nr * 65 + colc + j] = v0[j];
            tile[nr * 65 + colc + 4 + j] = v1[j];
        }
    }
    __syncthreads();
#pragma unroll
    for (int it = 0; it < 2; ++it) {
        int chunk = tid + it * 256;
        int cr = chunk >> 3, coln = (chunk & 7) * 8;
        int d = c0 + cr;
        bf16x8 o;
        if (kmode) {
            float mx = cst[(b * CH + d) * 2];
            float rs = cst[(b * CH + d) * 2 + 1];
#pragma unroll
            for (int j = 0; j < 8; j++) {
                float f = tile[(coln + j) * 65 + cr];
                o[j] = f2b(expf(f - mx) * rs);
            }
        } else {
#pragma unroll
            for (int j = 0; j < 8; j++) o[j] = f2b(tile[(coln + j) * 65 + cr]);
        }
        *(bf16x8*)(out + ((long)b * CH + d) * HW + n0 + coln) = o;
    }
}

// channel softmax on fp32 kvT k-part rows -> bf16 qT [n][c], * 512^-0.5
__global__ __launch_bounds__(256) void row_softmax_q(const float* __restrict__ kvT,
                                                     short* __restrict__ qT) {
    int row = blockIdx.x * 4 + (threadIdx.x >> 6);
    int lane = threadIdx.x & 63;
    int b = row >> 12, n = row & 4095;
    const float* p = kvT + ((long)b * HW + n) * (2 * CH);
    f32x4 v0 = *(const f32x4*)(p + lane * 8);
    f32x4 v1 = *(const f32x4*)(p + lane * 8 + 4);
    float f[8];
    float m = -1e30f;
#pragma unroll
    for (int j = 0; j < 4; j++) { f[j] = v0[j]; f[4 + j] = v1[j]; }
#pragma unroll
    for (int j = 0; j < 8; j++) m = fmaxf(m, f[j]);
    for (int off = 32; off; off >>= 1) m = fmaxf(m, __shfl_xor(m, off));
    float s = 0.f;
#pragma unroll
    for (int j = 0; j < 8; j++) { f[j] = expf(f[j] - m); s += f[j]; }
    for (int off = 32; off; off >>= 1) s += __shfl_xor(s, off);
    float inv = 0.044194173824159216f / s;  // 512^-0.5 / sum
    bf16x8 o;
#pragma unroll
    for (int j = 0; j < 8; j++) o[j] = f2b(f[j] * inv);
    *(bf16x8*)(qT + ((long)b * HW + n) * CH + lane * 8) = o;
}

// ---------------- GN2 stats on fp32 hT [n][512] ----------
__global__ __launch_bounds__(256) void gn2_stats(const float* __restrict__ hT,
                                                 float* __restrict__ stats) {
    int b = blockIdx.x >> 4, g = blockIdx.x & 15;
    int j = threadIdx.x & 31, nb0 = threadIdx.x >> 5;
    const float* p = hT + (long)b * HW * CH + g * GS + j;
    float s = 0.f, ss = 0.f;
    for (int n = nb0; n < HW; n += 8) { float f = p[(long)n * CH]; s += f; ss += f * f; }
    __shared__ float rs[256], rss[256];
    rs[threadIdx.x] = s; rss[threadIdx.x] = ss; __syncthreads();
    for (int off = 128; off; off >>= 1) {
        if (threadIdx.x < off) { rs[threadIdx.x] += rs[threadIdx.x + off]; rss[threadIdx.x] += rss[threadIdx.x + off]; }
        __syncthreads();
    }
    if (threadIdx.x == 0) {
        float mean = rs[0] / (GS * HW);
        float var = rss[0] / (GS * HW) - mean * mean;
        stats[(b * NG + g) * 2] = mean;
        stats[(b * NG + g) * 2 + 1] = rsqrtf(var + 1e-5f);
    }
}

// GN2 + exact GELU: fp32 hT in -> bf16 gbuf out
__global__ __launch_bounds__(256) void gn2_apply_gelu(const float* __restrict__ hT,
                                                      const float* __restrict__ stats,
                                                      const float* __restrict__ w,
                                                      const float* __restrict__ bias,
                                                      short* __restrict__ gbuf,
                                                      int total8) {
    int idx = blockIdx.x * 256 + threadIdx.x;
    if (idx >= total8) return;
    long flat = (long)idx * 8;
    int c = (int)(flat & (CH - 1));
    long bn = flat >> 9;
    int b = (int)(bn >> 12);
    int g = c >> 5;
    float mean = stats[(b * NG + g) * 2], rstd = stats[(b * NG + g) * 2 + 1];
    f32x4 v0 = *(const f32x4*)(hT + flat);
    f32x4 v1 = *(const f32x4*)(hT + flat + 4);
    bf16x8 o;
#pragma unroll
    for (int j = 0; j < 8; j++) {
        float xv = j < 4 ? v0[j] : v1[j - 4];
        float sw = w[c + j] * rstd;
        float sb = bias[c + j] - mean * sw;
        float y = xv * sw + sb;
        float gl = 0.5f * y * (1.f + erff(y * 0.70710678118654752f));
        o[j] = f2b(gl);
    }
    *(bf16x8*)(gbuf + flat) = o;
}

// ---------------- NT GEMM: C[M][N] = A[M][K] * B[N][K]^T, bf16 in, fp32 acc ----
// EPI 0: bf16 C[m][n]      1: fp32 + colBias      2: bf16 transposed C[n][m]
// EPI 3: fp32 + rowBias + fp32 residual            4: fp32 plain
template <int BM, int BN, int EPI>
__global__ __launch_bounds__(256) void gemm_nt(
    const short* __restrict__ A, long aStride, int lda,
    const short* __restrict__ B, long bStride, int ldb,
    int K,
    void* __restrict__ C, long cStride, int ldc,
    const float* __restrict__ bias,
    const float* __restrict__ resid, long rStride, int ldr) {
    constexpr int BK = 32;
    constexpr int LDK = 40;
    constexpr int TM = BM / 32;
    constexpr int TN = BN / 32;
    __shared__ short As[BM * LDK];
    __shared__ short Bs[BN * LDK];
    const int tid = threadIdx.x;
    const int wave = tid >> 6, lane = tid & 63;
    const int wm = wave >> 1, wn = wave & 1;
    const int lq = lane >> 4, lr = lane & 15;
    const int b = blockIdx.z;
    const int m0 = blockIdx.y * BM;
    const int n0 = blockIdx.x * BN;
    const short* Ab = A + (long)b * aStride;
    const short* Bb = B + (long)b * bStride;

    f32x4 acc[TM][TN];
#pragma unroll
    for (int i = 0; i < TM; i++)
#pragma unroll
        for (int j = 0; j < TN; j++) { acc[i][j][0] = 0.f; acc[i][j][1] = 0.f; acc[i][j][2] = 0.f; acc[i][j][3] = 0.f; }

    const int arow = tid >> 2;
    const int acol = (tid & 3) * 8;
    for (int k0 = 0; k0 < K; k0 += BK) {
        __syncthreads();
#pragma unroll
        for (int i = 0; i < BM / 64; ++i) {
            int r = arow + i * 64;
            bf16x8 v = *(const bf16x8*)(Ab + (long)(m0 + r) * lda + k0 + acol);
            *(bf16x8*)(As + r * LDK + acol) = v;
        }
#pragma unroll
        for (int i = 0; i < BN / 64; ++i) {
            int r = arow + i * 64;
            bf16x8 v = *(const bf16x8*)(Bb + (long)(n0 + r) * ldb + k0 + acol);
            *(bf16x8*)(Bs + r * LDK + acol) = v;
        }
        __syncthreads();
        bf16x8 af[TM], bfr[TN];
#pragma unroll
        for (int i = 0; i < TM; i++) af[i] = *(const bf16x8*)(As + (wm * TM * 16 + i * 16 + lr) * LDK + lq * 8);
#pragma unroll
        for (int j = 0; j < TN; j++) bfr[j] = *(const bf16x8*)(Bs + (wn * TN * 16 + j * 16 + lr) * LDK + lq * 8);
#pragma unroll
        for (int i = 0; i < TM; i++)
#pragma unroll
            for (int j = 0; j < TN; j++)
                acc[i][j] = __builtin_amdgcn_mfma_f32_16x16x32_bf16(af[i], bfr[j], acc[i][j], 0, 0, 0);
    }

    long cbase = (long)b * cStride;
#pragma unroll
    for (int i = 0; i < TM; i++) {
#pragma unroll
        for (int j = 0; j < TN; j++) {
            int gmBase = m0 + wm * TM * 16 + i * 16 + lq * 4;
            int gn = n0 + wn * TN * 16 + j * 16 + lr;
#pragma unroll
            for (int r = 0; r < 4; r++) {
                int gm = gmBase + r;
                float v = acc[i][j][r];
                if (EPI == 0) ((short*)C)[cbase + (long)gm * ldc + gn] = f2b(v);
                if (EPI == 1) ((float*)C)[cbase + (long)gm * ldc + gn] = v + bias[gn];
                if (EPI == 2) ((short*)C)[cbase + (long)gn * ldc + gm] = f2b(v);
                if (EPI == 3) ((float*)C)[cbase + (long)gm * ldc + gn] =
                                  v + bias[gm] + resid[(long)b * rStride + (long)gm * ldr + gn];
                if (EPI == 4) ((float*)C)[cbase + (long)gm * ldc + gn] = v;
            }
        }
    }
}

extern "C" void kernel_launch(void* const* d_in, const int* in_sizes, int n_in,
                              void* d_out, int out_size, void* d_ws, size_t ws_size,
                              hipStream_t stream) {
    (void)in_sizes; (void)n_in; (void)out_size;
    const float* x = (const float*)d_in[0];
    const float* n1w = (const float*)d_in[1];
    const float* n1b = (const float*)d_in[2];
    const float* kvw = (const float*)d_in[3];
    const float* kvb = (const float*)d_in[4];
    const float* n2w = (const float*)d_in[5];
    const float* n2b = (const float*)d_in[6];
    const float* ow = (const float*)d_in[7];
    const float* ob = (const float*)d_in[8];
    float* out = (float*)d_out;

    const long CN = (long)CH * HW;  // 2,097,152 elements per (b, tensor)
    auto need = [&](int nb) -> size_t {
        size_t s = 0;
        s += (size_t)nb * CN * 4;      // xn fp32
        s += (size_t)nb * CN * 2;      // qslot bf16 (xnT -> qT)
        s += (size_t)nb * 2 * CN * 4;  // kvT fp32
        s += (size_t)nb * CN * 2;      // K2 bf16 (-> gbuf)
        s += (size_t)nb * CN * 2;      // V2 bf16
        s += (size_t)nb * CN * 4;      // hT fp32
        s += (size_t)nb * CH * CH * 2; // ctT bf16
        s += (size_t)(3 * CH * CH) * 2;// weights bf16 (kvw 2C*C + ow C*C)
        s += (size_t)nb * (NG * 2 + 8 * CH * 2 + CH * 2 + NG * 2) * 4;
        return s + 4096;
    };
    int NB = 16;
    while (NB > 1 && need(NB) > ws_size) NB >>= 1;

    char* wp = (char*)d_ws;
    float* xn = (float*)wp;    wp += (size_t)NB * CN * 4;
    short* qslot = (short*)wp; wp += (size_t)NB * CN * 2;
    float* kvT = (float*)wp;   wp += (size_t)NB * 2 * CN * 4;
    short* K2 = (short*)wp;    wp += (size_t)NB * CN * 2;   // later: gelu out
    short* V2 = (short*)wp;    wp += (size_t)NB * CN * 2;
    float* hT = (float*)wp;    wp += (size_t)NB * CN * 4;
    short* ctT = (short*)wp;   wp += (size_t)NB * CH * CH * 2;
    short* wkv = (short*)wp;   wp += (size_t)2 * CH * CH * 2;
    short* wo = (short*)wp;    wp += (size_t)CH * CH * 2;
    float* st1 = (float*)wp;   wp += (size_t)NB * NG * 2 * 4;
    float* cpart = (float*)wp; wp += (size_t)NB * 8 * CH * 2 * 4;
    float* cst = (float*)wp;   wp += (size_t)NB * CH * 2 * 4;
    float* st2 = (float*)wp;

    // weights -> bf16 (every call; d_ws is re-poisoned between calls)
    cvt_w<<<(2 * CH * CH / 8 + 255) / 256, 256, 0, stream>>>(kvw, wkv, 2 * CH * CH / 8);
    cvt_w<<<(CH * CH / 8 + 255) / 256, 256, 0, stream>>>(ow, wo, CH * CH / 8);

    for (int b0 = 0; b0 < BATCH; b0 += NB) {
        const float* xb = x + (long)b0 * CN;
        float* outb = out + (long)b0 * CN;

        gn1_stats<<<NB * NG, 256, 0, stream>>>(xb, st1);
        gn1_apply<<<dim3(HW / 64, CH / 64, NB), 256, 0, stream>>>(xb, st1, n1w, n1b, xn, qslot);

        // kvT[n][o] = xnT[n][c] . kv_w[o][c] + kv_b  (fp32 out)
        gemm_nt<128, 128, 1><<<dim3(2 * CH / 128, HW / 128, NB), 256, 0, stream>>>(
            qslot, CN, CH,
            wkv, 0, CH,
            CH,
            kvT, 2 * CN, 2 * CH,
            kvb, nullptr, 0, 0);

        colstats_part<<<dim3(8, NB), 512, 0, stream>>>(kvT, cpart);
        colstats_reduce<<<NB, 512, 0, stream>>>(cpart, cst);
        transpose_apply<<<dim3(HW / 64, CH / 64, NB), 256, 0, stream>>>(kvT, cst, K2, 0, 1);
        transpose_apply<<<dim3(HW / 64, CH / 64, NB), 256, 0, stream>>>(kvT, cst, V2, CH, 0);
        row_softmax_q<<<NB * HW / 4, 256, 0, stream>>>(kvT, qslot);  // qT overwrites xnT

        // ctT[e][d] = sum_n K2[d][n] V2[e][n]   (bf16 transposed store)
        gemm_nt<64, 64, 2><<<dim3(CH / 64, CH / 64, NB), 256, 0, stream>>>(
            K2, CN, HW,
            V2, CN, HW,
            HW,
            ctT, (long)CH * CH, CH,
            nullptr, nullptr, 0, 0);

        // hT[n][e] = sum_d qT[n][d] ctT[e][d]   (fp32 out)
        gemm_nt<128, 128, 4><<<dim3(CH / 128, HW / 128, NB), 256, 0, stream>>>(
            qslot, CN, CH,
            ctT, (long)CH * CH, CH,
            CH,
            hT, CN, CH,
            nullptr, nullptr, 0, 0);

        gn2_stats<<<NB * NG, 256, 0, stream>>>(hT, st2);
        int total8 = NB * HW * CH / 8;
        gn2_apply_gelu<<<(total8 + 255) / 256, 256, 0, stream>>>(hT, st2, n2w, n2b, K2, total8);

        // out[o][n] = sum_c ow[o][c] g[n][c] + ob[o] + xn[o][n]  (fp32 out)
        gemm_nt<128, 128, 3><<<dim3(HW / 128, CH / 128, NB), 256, 0, stream>>>(
            wo, 0, CH,
            K2, CN, CH,
            CH,
            outb, CN, HW,
            ob, xn, CN, HW);
    }
}

// Round 3
// 1041.781 us; speedup vs baseline: 1.8128x; 1.8128x over previous
//
#include <hip/hip_runtime.h>
#include <math.h>

#define BATCH 16
#define CH 512
#define HW 4096
#define NG 16
#define GS 32

typedef __attribute__((ext_vector_type(8))) short bf16x8;
typedef __attribute__((ext_vector_type(2))) short s16x2;
typedef __attribute__((ext_vector_type(4))) float f32x4;

__device__ __forceinline__ float b2f(short s) {
    union { unsigned u; float f; } c;
    c.u = ((unsigned)(unsigned short)s) << 16;
    return c.f;
}
__device__ __forceinline__ short f2b(float f) {
    union { float f; unsigned u; } c; c.f = f;
    unsigned u = c.u + 0x7FFFu + ((c.u >> 16) & 1u);
    return (short)(u >> 16);
}

// convert fp32 weights -> bf16 (8 elements/thread)
__global__ __launch_bounds__(256) void cvt_w(const float* __restrict__ a,
                                             short* __restrict__ o, int n8) {
    int idx = blockIdx.x * 256 + threadIdx.x;
    if (idx >= n8) return;
    long f = (long)idx * 8;
    f32x4 v0 = *(const f32x4*)(a + f);
    f32x4 v1 = *(const f32x4*)(a + f + 4);
    bf16x8 ob;
#pragma unroll
    for (int j = 0; j < 4; j++) { ob[j] = f2b(v0[j]); ob[4 + j] = f2b(v1[j]); }
    *(bf16x8*)(o + f) = ob;
}

// ---------------- GroupNorm1 stats: two-stage, coalesced ----------
// stage 1: grid (8, NB*NG); each block sums a 16384-float chunk of one group
__global__ __launch_bounds__(256) void gn1_stats_part(const float* __restrict__ x,
                                                      float* __restrict__ part) {
    int chunk = blockIdx.x, bg = blockIdx.y;
    const float* p = x + (long)bg * (GS * HW) + chunk * 16384;
    float s = 0.f, ss = 0.f;
#pragma unroll
    for (int i = 0; i < 16; i++) {
        f32x4 v = *(const f32x4*)(p + (i * 256 + threadIdx.x) * 4);
#pragma unroll
        for (int j = 0; j < 4; j++) { s += v[j]; ss += v[j] * v[j]; }
    }
    __shared__ float rs[256], rss[256];
    rs[threadIdx.x] = s; rss[threadIdx.x] = ss; __syncthreads();
    for (int off = 128; off; off >>= 1) {
        if (threadIdx.x < off) { rs[threadIdx.x] += rs[threadIdx.x + off]; rss[threadIdx.x] += rss[threadIdx.x + off]; }
        __syncthreads();
    }
    if (threadIdx.x == 0) {
        part[(bg * 8 + chunk) * 2] = rs[0];
        part[(bg * 8 + chunk) * 2 + 1] = rss[0];
    }
}

__global__ __launch_bounds__(64) void gn1_stats_reduce(const float* __restrict__ part,
                                                       float* __restrict__ stats) {
    int bg = blockIdx.x;
    int c = threadIdx.x;
    float s = 0.f, ss = 0.f;
    if (c < 8) { s = part[(bg * 8 + c) * 2]; ss = part[(bg * 8 + c) * 2 + 1]; }
    for (int off = 4; off; off >>= 1) { s += __shfl_down(s, off); ss += __shfl_down(ss, off); }
    if (c == 0) {
        float mean = s / (GS * HW);
        float var = ss / (GS * HW) - mean * mean;
        stats[bg * 2] = mean;
        stats[bg * 2 + 1] = rsqrtf(var + 1e-5f);
    }
}

// GN1 apply: write xn fp32 [c][n] (residual) and xnT bf16 [n][c] (GEMM operand)
__global__ __launch_bounds__(256) void gn1_apply(const float* __restrict__ x,
                                                 const float* __restrict__ stats,
                                                 const float* __restrict__ w,
                                                 const float* __restrict__ bias,
                                                 float* __restrict__ xn,
                                                 short* __restrict__ xnT) {
    __shared__ short tile[64 * 66];
    int b = blockIdx.z, c0 = blockIdx.y * 64, n0 = blockIdx.x * 64;
    int tid = threadIdx.x;
#pragma unroll
    for (int it = 0; it < 2; ++it) {
        int chunk = tid + it * 256;
        int cr = chunk >> 3, colc = (chunk & 7) * 8;
        int c = c0 + cr;
        long base = ((long)b * CH + c) * HW + n0 + colc;
        f32x4 v0 = *(const f32x4*)(x + base);
        f32x4 v1 = *(const f32x4*)(x + base + 4);
        int g = c >> 5;
        float mean = stats[(b * NG + g) * 2], rstd = stats[(b * NG + g) * 2 + 1];
        float sw = w[c] * rstd;
        float sb = bias[c] - mean * sw;
        f32x4 o0, o1;
#pragma unroll
        for (int j = 0; j < 4; j++) { o0[j] = v0[j] * sw + sb; o1[j] = v1[j] * sw + sb; }
        *(f32x4*)(xn + base) = o0;
        *(f32x4*)(xn + base + 4) = o1;
#pragma unroll
        for (int k = 0; k < 4; k++) {
            s16x2 t2;
            t2[0] = f2b(k < 2 ? o0[2 * k] : o1[2 * k - 4]);
            t2[1] = f2b(k < 2 ? o0[2 * k + 1] : o1[2 * k - 3]);
            *(s16x2*)(tile + cr * 66 + colc + 2 * k) = t2;
        }
    }
    __syncthreads();
#pragma unroll
    for (int it = 0; it < 2; ++it) {
        int chunk = tid + it * 256;
        int nr = chunk >> 3, colc = (chunk & 7) * 8;
        bf16x8 o;
#pragma unroll
        for (int j = 0; j < 8; j++) o[j] = tile[(colc + j) * 66 + nr];
        *(bf16x8*)(xnT + ((long)b * HW + n0 + nr) * CH + c0 + colc) = o;
    }
}

// ---------------- column (spatial) softmax stats: branch-free online ----------
// grid (128, NB); each block: 32 rows, thread owns cols 2t, 2t+1
__global__ __launch_bounds__(256) void colstats_part(const float* __restrict__ kvT,
                                                     float* __restrict__ part) {
    int chunk = blockIdx.x, b = blockIdx.y;
    int t = threadIdx.x;
    const float* p = kvT + ((long)b * HW + chunk * 32) * (2 * CH) + 2 * t;
    float m0 = -1e30f, m1 = -1e30f, s0 = 0.f, s1 = 0.f;
#pragma unroll 8
    for (int r = 0; r < 32; r++) {
        float2 v = *(const float2*)(p + (long)r * (2 * CH));
        float nm0 = fmaxf(m0, v.x);
        s0 = s0 * __expf(m0 - nm0) + __expf(v.x - nm0); m0 = nm0;
        float nm1 = fmaxf(m1, v.y);
        s1 = s1 * __expf(m1 - nm1) + __expf(v.y - nm1); m1 = nm1;
    }
    f32x4 o; o[0] = m0; o[1] = s0; o[2] = m1; o[3] = s1;
    *(f32x4*)(part + (((long)(b * 128 + chunk)) * CH + 2 * t) * 2) = o;
}

__global__ __launch_bounds__(512) void colstats_reduce(const float* __restrict__ part,
                                                       float* __restrict__ cst) {
    int b = blockIdx.x, d = threadIdx.x;
    float m = -1e30f, s = 0.f;
#pragma unroll 8
    for (int c = 0; c < 128; c++) {
        float2 v = *(const float2*)(part + (((long)(b * 128 + c)) * CH + d) * 2);
        float nm = fmaxf(m, v.x);
        s = s * __expf(m - nm) + v.y * __expf(v.x - nm);
        m = nm;
    }
    cst[(b * CH + d) * 2] = m;
    cst[(b * CH + d) * 2 + 1] = 1.f / s;
}

// transpose fp32 kvT [n][1024] slice -> bf16 out [c][n]; kmode: spatial softmax
__global__ __launch_bounds__(256) void transpose_apply(const float* __restrict__ kvT,
                                                       const float* __restrict__ cst,
                                                       short* __restrict__ out,
                                                       int off, int kmode) {
    __shared__ float tile[64 * 65];
    int b = blockIdx.z, c0 = blockIdx.y * 64, n0 = blockIdx.x * 64;
    int tid = threadIdx.x;
#pragma unroll
    for (int it = 0; it < 2; ++it) {
        int chunk = tid + it * 256;
        int nr = chunk >> 3, colc = (chunk & 7) * 8;
        long base = ((long)b * HW + n0 + nr) * (2 * CH) + off + c0 + colc;
        f32x4 v0 = *(const f32x4*)(kvT + base);
        f32x4 v1 = *(const f32x4*)(kvT + base + 4);
#pragma unroll
        for (int j = 0; j < 4; j++) {
            tile[nr * 65 + colc + j] = v0[j];
            tile[nr * 65 + colc + 4 + j] = v1[j];
        }
    }
    __syncthreads();
#pragma unroll
    for (int it = 0; it < 2; ++it) {
        int chunk = tid + it * 256;
        int cr = chunk >> 3, coln = (chunk & 7) * 8;
        int d = c0 + cr;
        bf16x8 o;
        if (kmode) {
            float mx = cst[(b * CH + d) * 2];
            float rs = cst[(b * CH + d) * 2 + 1];
#pragma unroll
            for (int j = 0; j < 8; j++) {
                float f = tile[(coln + j) * 65 + cr];
                o[j] = f2b(__expf(f - mx) * rs);
            }
        } else {
#pragma unroll
            for (int j = 0; j < 8; j++) o[j] = f2b(tile[(coln + j) * 65 + cr]);
        }
        *(bf16x8*)(out + ((long)b * CH + d) * HW + n0 + coln) = o;
    }
}

// channel softmax on fp32 kvT k-part rows -> bf16 qT [n][c], * 512^-0.5
__global__ __launch_bounds__(256) void row_softmax_q(const float* __restrict__ kvT,
                                                     short* __restrict__ qT) {
    int row = blockIdx.x * 4 + (threadIdx.x >> 6);
    int lane = threadIdx.x & 63;
    int b = row >> 12, n = row & 4095;
    const float* p = kvT + ((long)b * HW + n) * (2 * CH);
    f32x4 v0 = *(const f32x4*)(p + lane * 8);
    f32x4 v1 = *(const f32x4*)(p + lane * 8 + 4);
    float f[8];
    float m = -1e30f;
#pragma unroll
    for (int j = 0; j < 4; j++) { f[j] = v0[j]; f[4 + j] = v1[j]; }
#pragma unroll
    for (int j = 0; j < 8; j++) m = fmaxf(m, f[j]);
    for (int off = 32; off; off >>= 1) m = fmaxf(m, __shfl_xor(m, off));
    float s = 0.f;
#pragma unroll
    for (int j = 0; j < 8; j++) { f[j] = __expf(f[j] - m); s += f[j]; }
    for (int off = 32; off; off >>= 1) s += __shfl_xor(s, off);
    float inv = 0.044194173824159216f / s;  // 512^-0.5 / sum
    bf16x8 o;
#pragma unroll
    for (int j = 0; j < 8; j++) o[j] = f2b(f[j] * inv);
    *(bf16x8*)(qT + ((long)b * HW + n) * CH + lane * 8) = o;
}

// ---------------- GN2 stats: two-stage, coalesced ----------
// stage 1: grid (64, NB); block covers 64 rows; thread owns cols 2t, 2t+1
__global__ __launch_bounds__(256) void gn2_stats_part(const float* __restrict__ hT,
                                                      float* __restrict__ part) {
    int chunk = blockIdx.x, b = blockIdx.y;
    int t = threadIdx.x;
    const float* p = hT + ((long)b * HW + chunk * 64) * CH + 2 * t;
    float s = 0.f, ss = 0.f;
#pragma unroll 8
    for (int r = 0; r < 64; r++) {
        float2 v = *(const float2*)(p + (long)r * CH);
        s += v.x + v.y;
        ss += v.x * v.x + v.y * v.y;
    }
    __shared__ float ls[256], lss[256];
    ls[t] = s; lss[t] = ss; __syncthreads();
    for (int off = 8; off; off >>= 1) {
        if ((t & 15) < off) { ls[t] += ls[t + off]; lss[t] += lss[t + off]; }
        __syncthreads();
    }
    if ((t & 15) == 0) {
        int g = t >> 4;
        part[((b * 64 + chunk) * NG + g) * 2] = ls[t];
        part[((b * 64 + chunk) * NG + g) * 2 + 1] = lss[t];
    }
}

__global__ __launch_bounds__(64) void gn2_stats_reduce(const float* __restrict__ part,
                                                       float* __restrict__ stats) {
    int bg = blockIdx.x;
    int b = bg >> 4, g = bg & 15;
    int c = threadIdx.x;
    float s = part[((b * 64 + c) * NG + g) * 2];
    float ss = part[((b * 64 + c) * NG + g) * 2 + 1];
    for (int off = 32; off; off >>= 1) { s += __shfl_down(s, off); ss += __shfl_down(ss, off); }
    if (c == 0) {
        float mean = s / (GS * HW);
        float var = ss / (GS * HW) - mean * mean;
        stats[bg * 2] = mean;
        stats[bg * 2 + 1] = rsqrtf(var + 1e-5f);
    }
}

// GN2 + exact GELU: fp32 hT in -> bf16 gbuf out
__global__ __launch_bounds__(256) void gn2_apply_gelu(const float* __restrict__ hT,
                                                      const float* __restrict__ stats,
                                                      const float* __restrict__ w,
                                                      const float* __restrict__ bias,
                                                      short* __restrict__ gbuf,
                                                      int total8) {
    int idx = blockIdx.x * 256 + threadIdx.x;
    if (idx >= total8) return;
    long flat = (long)idx * 8;
    int c = (int)(flat & (CH - 1));
    long bn = flat >> 9;
    int b = (int)(bn >> 12);
    int g = c >> 5;
    float mean = stats[(b * NG + g) * 2], rstd = stats[(b * NG + g) * 2 + 1];
    f32x4 v0 = *(const f32x4*)(hT + flat);
    f32x4 v1 = *(const f32x4*)(hT + flat + 4);
    bf16x8 o;
#pragma unroll
    for (int j = 0; j < 8; j++) {
        float xv = j < 4 ? v0[j] : v1[j - 4];
        float sw = w[c + j] * rstd;
        float sb = bias[c + j] - mean * sw;
        float y = xv * sw + sb;
        float gl = 0.5f * y * (1.f + erff(y * 0.70710678118654752f));
        o[j] = f2b(gl);
    }
    *(bf16x8*)(gbuf + flat) = o;
}

// ---------------- NT GEMM: C[M][N] = A[M][K] * B[N][K]^T, bf16 in, fp32 acc ----
// EPI 0: bf16 C[m][n]      1: fp32 + colBias      2: bf16 transposed C[n][m]
// EPI 3: fp32 + rowBias + fp32 residual            4: fp32 plain
template <int BM, int BN, int EPI>
__global__ __launch_bounds__(256) void gemm_nt(
    const short* __restrict__ A, long aStride, int lda,
    const short* __restrict__ B, long bStride, int ldb,
    int K,
    void* __restrict__ C, long cStride, int ldc,
    const float* __restrict__ bias,
    const float* __restrict__ resid, long rStride, int ldr) {
    constexpr int BK = 32;
    constexpr int LDK = 40;
    constexpr int TM = BM / 32;
    constexpr int TN = BN / 32;
    __shared__ short As[BM * LDK];
    __shared__ short Bs[BN * LDK];
    const int tid = threadIdx.x;
    const int wave = tid >> 6, lane = tid & 63;
    const int wm = wave >> 1, wn = wave & 1;
    const int lq = lane >> 4, lr = lane & 15;
    const int b = blockIdx.z;
    const int m0 = blockIdx.y * BM;
    const int n0 = blockIdx.x * BN;
    const short* Ab = A + (long)b * aStride;
    const short* Bb = B + (long)b * bStride;

    f32x4 acc[TM][TN];
#pragma unroll
    for (int i = 0; i < TM; i++)
#pragma unroll
        for (int j = 0; j < TN; j++) { acc[i][j][0] = 0.f; acc[i][j][1] = 0.f; acc[i][j][2] = 0.f; acc[i][j][3] = 0.f; }

    const int arow = tid >> 2;
    const int acol = (tid & 3) * 8;
    for (int k0 = 0; k0 < K; k0 += BK) {
        __syncthreads();
#pragma unroll
        for (int i = 0; i < BM / 64; ++i) {
            int r = arow + i * 64;
            bf16x8 v = *(const bf16x8*)(Ab + (long)(m0 + r) * lda + k0 + acol);
            *(bf16x8*)(As + r * LDK + acol) = v;
        }
#pragma unroll
        for (int i = 0; i < BN / 64; ++i) {
            int r = arow + i * 64;
            bf16x8 v = *(const bf16x8*)(Bb + (long)(n0 + r) * ldb + k0 + acol);
            *(bf16x8*)(Bs + r * LDK + acol) = v;
        }
        __syncthreads();
        bf16x8 af[TM], bfr[TN];
#pragma unroll
        for (int i = 0; i < TM; i++) af[i] = *(const bf16x8*)(As + (wm * TM * 16 + i * 16 + lr) * LDK + lq * 8);
#pragma unroll
        for (int j = 0; j < TN; j++) bfr[j] = *(const bf16x8*)(Bs + (wn * TN * 16 + j * 16 + lr) * LDK + lq * 8);
#pragma unroll
        for (int i = 0; i < TM; i++)
#pragma unroll
            for (int j = 0; j < TN; j++)
                acc[i][j] = __builtin_amdgcn_mfma_f32_16x16x32_bf16(af[i], bfr[j], acc[i][j], 0, 0, 0);
    }

    long cbase = (long)b * cStride;
#pragma unroll
    for (int i = 0; i < TM; i++) {
#pragma unroll
        for (int j = 0; j < TN; j++) {
            int gmBase = m0 + wm * TM * 16 + i * 16 + lq * 4;
            int gn = n0 + wn * TN * 16 + j * 16 + lr;
#pragma unroll
            for (int r = 0; r < 4; r++) {
                int gm = gmBase + r;
                float v = acc[i][j][r];
                if (EPI == 0) ((short*)C)[cbase + (long)gm * ldc + gn] = f2b(v);
                if (EPI == 1) ((float*)C)[cbase + (long)gm * ldc + gn] = v + bias[gn];
                if (EPI == 2) ((short*)C)[cbase + (long)gn * ldc + gm] = f2b(v);
                if (EPI == 3) ((float*)C)[cbase + (long)gm * ldc + gn] =
                                  v + bias[gm] + resid[(long)b * rStride + (long)gm * ldr + gn];
                if (EPI == 4) ((float*)C)[cbase + (long)gm * ldc + gn] = v;
            }
        }
    }
}

extern "C" void kernel_launch(void* const* d_in, const int* in_sizes, int n_in,
                              void* d_out, int out_size, void* d_ws, size_t ws_size,
                              hipStream_t stream) {
    (void)in_sizes; (void)n_in; (void)out_size;
    const float* x = (const float*)d_in[0];
    const float* n1w = (const float*)d_in[1];
    const float* n1b = (const float*)d_in[2];
    const float* kvw = (const float*)d_in[3];
    const float* kvb = (const float*)d_in[4];
    const float* n2w = (const float*)d_in[5];
    const float* n2b = (const float*)d_in[6];
    const float* ow = (const float*)d_in[7];
    const float* ob = (const float*)d_in[8];
    float* out = (float*)d_out;

    const long CN = (long)CH * HW;  // 2,097,152 elements per (b, tensor)
    auto need = [&](int nb) -> size_t {
        size_t s = 0;
        s += (size_t)nb * CN * 4;      // xn fp32
        s += (size_t)nb * CN * 2;      // qslot bf16 (xnT -> qT)
        s += (size_t)nb * 2 * CN * 4;  // kvT fp32
        s += (size_t)nb * CN * 2;      // K2 bf16 (-> gbuf)
        s += (size_t)nb * CN * 2;      // V2 bf16
        s += (size_t)nb * CN * 4;      // hT fp32
        s += (size_t)nb * CH * CH * 2; // ctT bf16
        s += (size_t)(3 * CH * CH) * 2;// weights bf16
        s += (size_t)nb * (128 * CH * 2 + 64 * NG * 2 + NG * 8 * 2 + NG * 2 + CH * 2 + NG * 2) * 4;
        return s + 8192;
    };
    int NB = 16;
    while (NB > 1 && need(NB) > ws_size) NB >>= 1;

    char* wp = (char*)d_ws;
    float* xn = (float*)wp;    wp += (size_t)NB * CN * 4;
    short* qslot = (short*)wp; wp += (size_t)NB * CN * 2;
    float* kvT = (float*)wp;   wp += (size_t)NB * 2 * CN * 4;
    short* K2 = (short*)wp;    wp += (size_t)NB * CN * 2;   // later: gelu out
    short* V2 = (short*)wp;    wp += (size_t)NB * CN * 2;
    float* hT = (float*)wp;    wp += (size_t)NB * CN * 4;
    short* ctT = (short*)wp;   wp += (size_t)NB * CH * CH * 2;
    short* wkv = (short*)wp;   wp += (size_t)2 * CH * CH * 2;
    short* wo = (short*)wp;    wp += (size_t)CH * CH * 2;
    float* g1part = (float*)wp; wp += (size_t)NB * NG * 8 * 2 * 4;
    float* st1 = (float*)wp;    wp += (size_t)NB * NG * 2 * 4;
    float* cpart = (float*)wp;  wp += (size_t)NB * 128 * CH * 2 * 4;
    float* cst = (float*)wp;    wp += (size_t)NB * CH * 2 * 4;
    float* g2part = (float*)wp; wp += (size_t)NB * 64 * NG * 2 * 4;
    float* st2 = (float*)wp;

    // weights -> bf16 (every call; d_ws is re-poisoned between calls)
    cvt_w<<<(2 * CH * CH / 8 + 255) / 256, 256, 0, stream>>>(kvw, wkv, 2 * CH * CH / 8);
    cvt_w<<<(CH * CH / 8 + 255) / 256, 256, 0, stream>>>(ow, wo, CH * CH / 8);

    for (int b0 = 0; b0 < BATCH; b0 += NB) {
        const float* xb = x + (long)b0 * CN;
        float* outb = out + (long)b0 * CN;

        gn1_stats_part<<<dim3(8, NB * NG), 256, 0, stream>>>(xb, g1part);
        gn1_stats_reduce<<<NB * NG, 64, 0, stream>>>(g1part, st1);
        gn1_apply<<<dim3(HW / 64, CH / 64, NB), 256, 0, stream>>>(xb, st1, n1w, n1b, xn, qslot);

        // kvT[n][o] = xnT[n][c] . kv_w[o][c] + kv_b  (fp32 out)
        gemm_nt<128, 128, 1><<<dim3(2 * CH / 128, HW / 128, NB), 256, 0, stream>>>(
            qslot, CN, CH,
            wkv, 0, CH,
            CH,
            kvT, 2 * CN, 2 * CH,
            kvb, nullptr, 0, 0);

        colstats_part<<<dim3(128, NB), 256, 0, stream>>>(kvT, cpart);
        colstats_reduce<<<NB, 512, 0, stream>>>(cpart, cst);
        transpose_apply<<<dim3(HW / 64, CH / 64, NB), 256, 0, stream>>>(kvT, cst, K2, 0, 1);
        transpose_apply<<<dim3(HW / 64, CH / 64, NB), 256, 0, stream>>>(kvT, cst, V2, CH, 0);
        row_softmax_q<<<NB * HW / 4, 256, 0, stream>>>(kvT, qslot);  // qT overwrites xnT

        // ctT[e][d] = sum_n K2[d][n] V2[e][n]   (bf16 transposed store)
        gemm_nt<64, 64, 2><<<dim3(CH / 64, CH / 64, NB), 256, 0, stream>>>(
            K2, CN, HW,
            V2, CN, HW,
            HW,
            ctT, (long)CH * CH, CH,
            nullptr, nullptr, 0, 0);

        // hT[n][e] = sum_d qT[n][d] ctT[e][d]   (fp32 out)
        gemm_nt<128, 128, 4><<<dim3(CH / 128, HW / 128, NB), 256, 0, stream>>>(
            qslot, CN, CH,
            ctT, (long)CH * CH, CH,
            CH,
            hT, CN, CH,
            nullptr, nullptr, 0, 0);

        gn2_stats_part<<<dim3(64, NB), 256, 0, stream>>>(hT, g2part);
        gn2_stats_reduce<<<NB * NG, 64, 0, stream>>>(g2part, st2);
        int total8 = NB * HW * CH / 8;
        gn2_apply_gelu<<<(total8 + 255) / 256, 256, 0, stream>>>(hT, st2, n2w, n2b, K2, total8);

        // out[o][n] = sum_c ow[o][c] g[n][c] + ob[o] + xn[o][n]  (fp32 out)
        gemm_nt<128, 128, 3><<<dim3(HW / 128, CH / 128, NB), 256, 0, stream>>>(
            wo, 0, CH,
            K2, CN, CH,
            CH,
            outb, CN, HW,
            ob, xn, CN, HW);
    }
}